// Round 10
// baseline (144.457 us; speedup 1.0000x reference)
//
#include <hip/hip_runtime.h>

// Problem constants (fixed by the reference)
#define BATCH 128
#define C 64
#define L 4096
#define K 31

#define NT 256
#define CG 16                // channel groups (blocks split over channels)
#define CPB (C / CG)         // 4 channels per block
#define RW 16                // outputs per lane
#define WTILE 1024           // outputs per wave (64 lanes * RW); block = 4 waves = L

typedef float floatx4 __attribute__((ext_vector_type(4)));

__device__ __forceinline__ floatx4 ld4(const float* p) {
    return *reinterpret_cast<const floatx4*>(p);
}

// ---- K1: Sp[cg][b][l] = sum_{i in cg} sum_k w[i,k] * x[b,i,l+15-k]
// RW=16 shuffle-window: lane owns 16 floats; window = shfl_up(1) | own |
// shfl_down(1) -> 30 shuffles / 16 outputs (vs 5/output at RW=8), fixups
// only on lanes 0 and 63. Halo regs are zero-init ONCE outside the loop:
// safe because halo loads are wave-uniformly always-or-never executed.
__global__ __launch_bounds__(NT, 4)
void computeS_kernel(const float* __restrict__ x,
                     const float* __restrict__ w,
                     float* __restrict__ Sp) {
    const int tid  = threadIdx.x;
    const int wv   = tid >> 6;
    const int lane = tid & 63;
    const int b    = blockIdx.x;          // 0..127
    const int cg   = blockIdx.y;          // 0..15
    const int W0   = wv * WTILE;          // wave's first output
    const int l0   = W0 + lane * RW;      // lane's first output
    const int i0   = cg * CPB;
    const float* xb = x + (long)b * C * L;

    const bool ln0  = (lane == 0);
    const bool ln63 = (lane == 63);
    const bool leftOK  = (W0 > 0);             // wave-uniform
    const bool rightOK = (W0 + WTILE < L);     // wave-uniform

    float acc[RW];
#pragma unroll
    for (int r = 0; r < RW; ++r) acc[r] = 0.f;

    // halo registers: only lane0 (left) / lane63 (right) ever load them;
    // at array edges they stay zero (loads skipped wave-uniformly).
    floatx4 h0 = 0.f, h1 = 0.f, h2 = 0.f, h3 = 0.f;

    // prologue: own load for first channel
    const float* p0 = xb + (long)i0 * L + l0;
    floatx4 o0 = ld4(p0), o1 = ld4(p0 + 4), o2 = ld4(p0 + 8), o3 = ld4(p0 + 12);

#pragma unroll
    for (int c = 0; c < CPB; ++c) {
        const int i = i0 + c;
        const float* xi = xb + (long)i * L;

        // halo loads for this channel (issued early; consumed after shuffles)
        if (ln0 && leftOK) {
            const float* hp = xi + W0 - 16;   // -> win[0..15]
            h0 = ld4(hp); h1 = ld4(hp + 4); h2 = ld4(hp + 8); h3 = ld4(hp + 12);
        }
        if (ln63 && rightOK) {
            const float* hp = xi + W0 + WTILE;   // -> win[32..47]
            h0 = ld4(hp); h1 = ld4(hp + 4); h2 = ld4(hp + 8); h3 = ld4(hp + 12);
        }

        // prefetch next channel's own data (1-deep)
        floatx4 n0 = o0, n1 = o1, n2 = o2, n3 = o3;
        if (c + 1 < CPB) {
            const float* np = xi + L + l0;
            n0 = ld4(np); n1 = ld4(np + 4); n2 = ld4(np + 8); n3 = ld4(np + 12);
        }

        // window win[m] = x[l0 - 16 + m]; own occupies win[16..31]
        float win[48];
        *reinterpret_cast<floatx4*>(&win[16]) = o0;
        *reinterpret_cast<floatx4*>(&win[20]) = o1;
        *reinterpret_cast<floatx4*>(&win[24]) = o2;
        *reinterpret_cast<floatx4*>(&win[28]) = o3;
#pragma unroll
        for (int j = 0; j < RW; ++j) {
            const float oj = win[16 + j];
            if (j > 0)  win[j]      = __shfl_up(oj, 1, 64);    // win[1..15]  (lane0 fixed below)
            if (j < 15) win[32 + j] = __shfl_down(oj, 1, 64);  // win[32..46] (lane63 fixed below)
        }
        win[0] = 0.f; win[47] = 0.f;   // unused by FMAs (indices 1..46)
        if (ln0) {
            *reinterpret_cast<floatx4*>(&win[0])  = h0;
            *reinterpret_cast<floatx4*>(&win[4])  = h1;
            *reinterpret_cast<floatx4*>(&win[8])  = h2;
            *reinterpret_cast<floatx4*>(&win[12]) = h3;
        }
        if (ln63) {
            *reinterpret_cast<floatx4*>(&win[32]) = h0;
            *reinterpret_cast<floatx4*>(&win[36]) = h1;
            *reinterpret_cast<floatx4*>(&win[40]) = h2;
            *reinterpret_cast<floatx4*>(&win[44]) = h3;
        }

        const float* wp = w + i * K;   // wave-uniform -> scalar loads
#pragma unroll
        for (int k = 0; k < K; ++k) {
            const float wk = wp[k];
#pragma unroll
            for (int r = 0; r < RW; ++r)
                acc[r] += wk * win[r + 31 - k];
        }

        o0 = n0; o1 = n1; o2 = n2; o3 = n3;
    }

    float* sp = Sp + ((long)cg * BATCH + b) * L + l0;
#pragma unroll
    for (int r = 0; r < RW; r += 4) {
        floatx4 v;
        v.x = acc[r]; v.y = acc[r + 1]; v.z = acc[r + 2]; v.w = acc[r + 3];
        *reinterpret_cast<floatx4*>(sp + r) = v;
    }
}

// ---- K2: out[b,o,l] = sum_cg Sp[cg][b][l] — dense streaming broadcast.
__global__ __launch_bounds__(NT)
void broadcast_kernel(const float* __restrict__ Sp,
                      float* __restrict__ out) {
    const int lane = threadIdx.x & 63;
    const int og   = threadIdx.x >> 6;            // 0..3
    const int b    = blockIdx.y;
    const int l4   = blockIdx.x * 64 + lane;      // float4 column index
    const long sbase = (long)b * L + (long)l4 * 4;

    floatx4 v = *reinterpret_cast<const floatx4*>(Sp + sbase);
#pragma unroll
    for (int cg = 1; cg < CG; ++cg)
        v += *reinterpret_cast<const floatx4*>(Sp + (long)cg * BATCH * L + sbase);

    float* ob = out + ((long)b * C + og * 16) * L + (long)l4 * 4;
#pragma unroll
    for (int o = 0; o < 16; ++o)
        __builtin_nontemporal_store(v, reinterpret_cast<floatx4*>(ob + (long)o * L));
}

// ---- Fallback (proven round-3 fused kernel) if ws too small ----
#define FB_R 4
#define FB_TILE (NT * FB_R)
#define FB_WIN 36
__global__ __launch_bounds__(NT)
void fused_kernel(const float* __restrict__ x,
                  const float* __restrict__ w,
                  float* __restrict__ out) {
    const int tid = threadIdx.x;
    const int tile = blockIdx.x;
    const int b = blockIdx.y;
    const int l0 = tile * FB_TILE + tid * FB_R;
    float acc[FB_R] = {0.f, 0.f, 0.f, 0.f};
    const float* xb = x + (long)b * C * L;
    const bool interior = (l0 >= 16) && (l0 + 20 <= L);
    if (interior) {
        const float* xw = xb + (l0 - 16);
#pragma unroll 2
        for (int i = 0; i < C; ++i) {
            float win[FB_WIN];
            const floatx4* p = reinterpret_cast<const floatx4*>(xw + (long)i * L);
#pragma unroll
            for (int j = 0; j < FB_WIN / 4; ++j)
                reinterpret_cast<floatx4*>(win)[j] = p[j];
            const float* wp = w + i * K;
#pragma unroll
            for (int k = 0; k < K; ++k) {
                const float wk = wp[k];
#pragma unroll
                for (int r = 0; r < FB_R; ++r)
                    acc[r] += wk * win[r + 31 - k];
            }
        }
    } else {
        for (int i = 0; i < C; ++i) {
            const float* xi = xb + (long)i * L;
            float win[FB_WIN];
#pragma unroll
            for (int j = 0; j < FB_WIN; ++j) {
                const int g = l0 - 16 + j;
                win[j] = (g >= 0 && g < L) ? xi[g] : 0.f;
            }
            const float* wp = w + i * K;
#pragma unroll
            for (int k = 0; k < K; ++k) {
                const float wk = wp[k];
#pragma unroll
                for (int r = 0; r < FB_R; ++r)
                    acc[r] += wk * win[r + 31 - k];
            }
        }
    }
    float* op = out + (long)b * C * L + l0;
    floatx4 v; v.x = acc[0]; v.y = acc[1]; v.z = acc[2]; v.w = acc[3];
#pragma unroll
    for (int o = 0; o < C; ++o)
        __builtin_nontemporal_store(v, reinterpret_cast<floatx4*>(op + (long)o * L));
}

extern "C" void kernel_launch(void* const* d_in, const int* in_sizes, int n_in,
                              void* d_out, int out_size, void* d_ws, size_t ws_size,
                              hipStream_t stream) {
    const float* x = (const float*)d_in[0];   // [B, C, L] fp32
    const float* w = (const float*)d_in[1];   // [C, C, K] fp32; o=0 slice used
    float* out = (float*)d_out;               // [B, C, L] fp32

    const size_t sp_bytes = (size_t)CG * BATCH * L * sizeof(float);   // 32 MB
    if (ws_size >= sp_bytes) {
        float* Sp = (float*)d_ws;
        dim3 grid1(BATCH, CG);                    // 128 x 16 = 2048 blocks
        computeS_kernel<<<grid1, NT, 0, stream>>>(x, w, Sp);
        dim3 grid2(L / 256, BATCH);               // 2048 blocks
        broadcast_kernel<<<grid2, NT, 0, stream>>>(Sp, out);
    } else {
        dim3 grid(L / FB_TILE, BATCH);
        fused_kernel<<<grid, NT, 0, stream>>>(x, w, out);
    }
}

// Round 11
// 141.954 us; speedup vs baseline: 1.0176x; 1.0176x over previous
//
#include <hip/hip_runtime.h>

// Problem constants (fixed by the reference)
#define BATCH 128
#define C 64
#define L 4096
#define K 31

#define NT 256
#define NWAVE 4
#define CG 16                // channel groups (blocks split over channels)
#define CPB (C / CG)         // 4 channels per block
#define RW 16                // samples/outputs per lane
#define WTILE 1024           // outputs per wave; block (4 waves) covers all of L

typedef float floatx4 __attribute__((ext_vector_type(4)));

__device__ __forceinline__ floatx4 ld4(const float* p) {
    return *reinterpret_cast<const floatx4*>(p);
}

// ---- K1: Sp[cg][b][l] = sum_{i in cg} sum_k w[i,k] * x[b,i,l+15-k]
// Scatter formulation: lane owns 16 samples; P[j] (j=0..45) accumulates the
// contribution of own samples to output positions l0-15+j across ALL channels
// (conv is linear, so cross-lane exchange hoists out of the loop). Inner loop:
// P[s+k] += w[k]*own[s] — static indices only, no shuffles, no halo loads,
// no divergence. One end-phase: 30 shuffles + LDS wave-edge exchange.
__global__ __launch_bounds__(NT, 4)
void computeS_kernel(const float* __restrict__ x,
                     const float* __restrict__ w,
                     float* __restrict__ Sp) {
    __shared__ float ex1[NWAVE][16];   // lane63 P[31..45] -> next wave's lane0
    __shared__ float ex2[NWAVE][16];   // lane0  P[0..14]  -> prev wave's lane63

    const int tid  = threadIdx.x;
    const int wv   = tid >> 6;
    const int lane = tid & 63;
    const int b    = blockIdx.x;          // 0..127
    const int cg   = blockIdx.y;          // 0..15
    const int l0   = wv * WTILE + lane * RW;
    const int i0   = cg * CPB;
    const float* xb = x + (long)b * C * L;

    float P[46];
#pragma unroll
    for (int j = 0; j < 46; ++j) P[j] = 0.f;

    // prologue: own samples for first channel
    const float* p0 = xb + (long)i0 * L + l0;
    floatx4 o0 = ld4(p0), o1 = ld4(p0 + 4), o2 = ld4(p0 + 8), o3 = ld4(p0 + 12);

#pragma unroll
    for (int c = 0; c < CPB; ++c) {
        const int i = i0 + c;

        // 1-deep prefetch of next channel's own samples
        floatx4 n0 = o0, n1 = o1, n2 = o2, n3 = o3;
        if (c + 1 < CPB) {
            const float* np = xb + (long)(i + 1) * L + l0;
            n0 = ld4(np); n1 = ld4(np + 4); n2 = ld4(np + 8); n3 = ld4(np + 12);
        }

        const float own[RW] = {o0.x, o0.y, o0.z, o0.w,
                               o1.x, o1.y, o1.z, o1.w,
                               o2.x, o2.y, o2.z, o2.w,
                               o3.x, o3.y, o3.z, o3.w};

        const float* wp = w + i * K;   // wave-uniform -> scalar loads
#pragma unroll
        for (int k = 0; k < K; ++k) {
            const float wk = wp[k];
#pragma unroll
            for (int s = 0; s < RW; ++s)
                P[s + k] += wk * own[s];   // output l0 + s + k - 15
        }

        o0 = n0; o1 = n1; o2 = n2; o3 = n3;
    }

    // ---- wave-edge partials exchange (once per kernel) ----
    if (lane == 63) {
#pragma unroll
        for (int j = 0; j < 15; ++j) ex1[wv][j] = P[31 + j];
    }
    if (lane == 0) {
#pragma unroll
        for (int j = 0; j < 15; ++j) ex2[wv][j] = P[j];
    }
    __syncthreads();

    float res[RW];
#pragma unroll
    for (int r = 0; r < RW; ++r) res[r] = P[15 + r];

    // from left neighbor (lane-1; wave boundary via LDS; array edge -> 0)
#pragma unroll
    for (int r = 0; r < 15; ++r) {
        float v = __shfl_up(P[31 + r], 1, 64);
        if (lane == 0) v = (wv > 0) ? ex1[wv - 1][r] : 0.f;
        res[r] += v;
    }
    // from right neighbor (lane+1; wave boundary via LDS; array edge -> 0)
#pragma unroll
    for (int r = 1; r < RW; ++r) {
        float v = __shfl_down(P[r - 1], 1, 64);
        if (lane == 63) v = (wv < NWAVE - 1) ? ex2[wv + 1][r - 1] : 0.f;
        res[r] += v;
    }

    float* sp = Sp + ((long)cg * BATCH + b) * L + l0;
#pragma unroll
    for (int r = 0; r < RW; r += 4) {
        floatx4 v;
        v.x = res[r]; v.y = res[r + 1]; v.z = res[r + 2]; v.w = res[r + 3];
        *reinterpret_cast<floatx4*>(sp + r) = v;
    }
}

// ---- K2: out[b,o,l] = sum_cg Sp[cg][b][l] — dense streaming broadcast.
__global__ __launch_bounds__(NT)
void broadcast_kernel(const float* __restrict__ Sp,
                      float* __restrict__ out) {
    const int lane = threadIdx.x & 63;
    const int og   = threadIdx.x >> 6;            // 0..3
    const int b    = blockIdx.y;
    const int l4   = blockIdx.x * 64 + lane;      // float4 column index
    const long sbase = (long)b * L + (long)l4 * 4;

    floatx4 v = *reinterpret_cast<const floatx4*>(Sp + sbase);
#pragma unroll
    for (int cg = 1; cg < CG; ++cg)
        v += *reinterpret_cast<const floatx4*>(Sp + (long)cg * BATCH * L + sbase);

    float* ob = out + ((long)b * C + og * 16) * L + (long)l4 * 4;
#pragma unroll
    for (int o = 0; o < 16; ++o)
        __builtin_nontemporal_store(v, reinterpret_cast<floatx4*>(ob + (long)o * L));
}

// ---- Fallback (proven round-3 fused kernel) if ws too small ----
#define FB_R 4
#define FB_TILE (NT * FB_R)
#define FB_WIN 36
__global__ __launch_bounds__(NT)
void fused_kernel(const float* __restrict__ x,
                  const float* __restrict__ w,
                  float* __restrict__ out) {
    const int tid = threadIdx.x;
    const int tile = blockIdx.x;
    const int b = blockIdx.y;
    const int l0 = tile * FB_TILE + tid * FB_R;
    float acc[FB_R] = {0.f, 0.f, 0.f, 0.f};
    const float* xb = x + (long)b * C * L;
    const bool interior = (l0 >= 16) && (l0 + 20 <= L);
    if (interior) {
        const float* xw = xb + (l0 - 16);
#pragma unroll 2
        for (int i = 0; i < C; ++i) {
            float win[FB_WIN];
            const floatx4* p = reinterpret_cast<const floatx4*>(xw + (long)i * L);
#pragma unroll
            for (int j = 0; j < FB_WIN / 4; ++j)
                reinterpret_cast<floatx4*>(win)[j] = p[j];
            const float* wp = w + i * K;
#pragma unroll
            for (int k = 0; k < K; ++k) {
                const float wk = wp[k];
#pragma unroll
                for (int r = 0; r < FB_R; ++r)
                    acc[r] += wk * win[r + 31 - k];
            }
        }
    } else {
        for (int i = 0; i < C; ++i) {
            const float* xi = xb + (long)i * L;
            float win[FB_WIN];
#pragma unroll
            for (int j = 0; j < FB_WIN; ++j) {
                const int g = l0 - 16 + j;
                win[j] = (g >= 0 && g < L) ? xi[g] : 0.f;
            }
            const float* wp = w + i * K;
#pragma unroll
            for (int k = 0; k < K; ++k) {
                const float wk = wp[k];
#pragma unroll
                for (int r = 0; r < FB_R; ++r)
                    acc[r] += wk * win[r + 31 - k];
            }
        }
    }
    float* op = out + (long)b * C * L + l0;
    floatx4 v; v.x = acc[0]; v.y = acc[1]; v.z = acc[2]; v.w = acc[3];
#pragma unroll
    for (int o = 0; o < C; ++o)
        __builtin_nontemporal_store(v, reinterpret_cast<floatx4*>(op + (long)o * L));
}

extern "C" void kernel_launch(void* const* d_in, const int* in_sizes, int n_in,
                              void* d_out, int out_size, void* d_ws, size_t ws_size,
                              hipStream_t stream) {
    const float* x = (const float*)d_in[0];   // [B, C, L] fp32
    const float* w = (const float*)d_in[1];   // [C, C, K] fp32; o=0 slice used
    float* out = (float*)d_out;               // [B, C, L] fp32

    const size_t sp_bytes = (size_t)CG * BATCH * L * sizeof(float);   // 32 MB
    if (ws_size >= sp_bytes) {
        float* Sp = (float*)d_ws;
        dim3 grid1(BATCH, CG);                    // 128 x 16 = 2048 blocks
        computeS_kernel<<<grid1, NT, 0, stream>>>(x, w, Sp);
        dim3 grid2(L / 256, BATCH);               // 2048 blocks
        broadcast_kernel<<<grid2, NT, 0, stream>>>(Sp, out);
    } else {
        dim3 grid(L / FB_TILE, BATCH);
        fused_kernel<<<grid, NT, 0, stream>>>(x, w, out);
    }
}

// Round 13
// 60.985 us; speedup vs baseline: 2.3687x; 2.3277x over previous
//
#include <hip/hip_runtime.h>

// Problem constants (fixed by the reference)
#define BATCH 128
#define C 64
#define L 4096
#define K 31

#define NT 512               // 8 waves; one block covers all of L
#define NWAVE 8
#define CG 8                 // channel groups (blocks split over channels)
#define CPB (C / CG)         // 8 channels per block
#define RW 8                 // samples/outputs per lane
#define WTILE 512            // outputs per wave (64 lanes * RW); 8 waves = L

typedef float floatx4 __attribute__((ext_vector_type(4)));

__device__ __forceinline__ floatx4 ld4(const float* p) {
    return *reinterpret_cast<const floatx4*>(p);
}

// ---- K1: Sp[cg][b][l] = sum_{i in cg} sum_k w[i,k] * x[b,i,l+15-k]
// Scatter formulation (fits 64 VGPR): lane owns 8 samples; P[j] j=0..37
// accumulates contributions to output l0-15+j across all channels.
// K=31 spans TWO lanes each side at RW=8, so the end-phase exchange is
// 2-hop: res[r] = P[15+r] + up1(P[23+r]) + up2(P[31+r]) + down1(P[7+r])
// + down2(P[r-1]); lanes 0,1 / 62,63 patch via LDS from adjacent waves.
#define KSTEP(k) { const float wk = wp[k];                              \
    P[(k)+0] += wk * o0.x; P[(k)+1] += wk * o0.y;                       \
    P[(k)+2] += wk * o0.z; P[(k)+3] += wk * o0.w;                       \
    P[(k)+4] += wk * o1.x; P[(k)+5] += wk * o1.y;                       \
    P[(k)+6] += wk * o1.z; P[(k)+7] += wk * o1.w; }

__global__ __launch_bounds__(NT, 2)
void computeS_kernel(const float* __restrict__ x,
                     const float* __restrict__ w,
                     float* __restrict__ Sp) {
    __shared__ float exL1[NWAVE][8];   // lane63's P[23..30]
    __shared__ float exL2a[NWAVE][8];  // lane62's P[31..37]
    __shared__ float exL2b[NWAVE][8];  // lane63's P[31..37]
    __shared__ float exR1[NWAVE][8];   // lane0's  P[7..14]
    __shared__ float exR2a[NWAVE][8];  // lane1's  P[0..6]
    __shared__ float exR2b[NWAVE][8];  // lane0's  P[0..6]

    const int tid  = threadIdx.x;
    const int wv   = tid >> 6;
    const int lane = tid & 63;
    const int b    = blockIdx.x;          // 0..127
    const int cg   = blockIdx.y;          // 0..7
    const int l0   = wv * WTILE + lane * RW;
    const int i0   = cg * CPB;
    const float* xb = x + (long)b * C * L;

    float P[38] = {};   // P[j] <-> output l0 - 15 + j

    const float* xi = xb + (long)i0 * L + l0;
    floatx4 o0 = ld4(xi), o1 = ld4(xi + 4);

    for (int c = 0; c < CPB; ++c) {
        // 1-deep prefetch of next channel's own samples
        floatx4 n0 = o0, n1 = o1;
        if (c + 1 < CPB) { n0 = ld4(xi + L); n1 = ld4(xi + L + 4); }

        const float* wp = w + (i0 + c) * K;   // block-uniform -> s_load
        KSTEP(0)  KSTEP(1)  KSTEP(2)  KSTEP(3)  KSTEP(4)  KSTEP(5)
        KSTEP(6)  KSTEP(7)  KSTEP(8)  KSTEP(9)  KSTEP(10) KSTEP(11)
        KSTEP(12) KSTEP(13) KSTEP(14) KSTEP(15) KSTEP(16) KSTEP(17)
        KSTEP(18) KSTEP(19) KSTEP(20) KSTEP(21) KSTEP(22) KSTEP(23)
        KSTEP(24) KSTEP(25) KSTEP(26) KSTEP(27) KSTEP(28) KSTEP(29)
        KSTEP(30)

        o0 = n0; o1 = n1;
        xi += L;
    }

    // ---- wave-edge partials to LDS (once per kernel) ----
    if (lane == 63) {
#pragma unroll
        for (int j = 0; j < 8; ++j) exL1[wv][j] = P[23 + j];
#pragma unroll
        for (int j = 0; j < 7; ++j) exL2b[wv][j] = P[31 + j];
    }
    if (lane == 62) {
#pragma unroll
        for (int j = 0; j < 7; ++j) exL2a[wv][j] = P[31 + j];
    }
    if (lane == 0) {
#pragma unroll
        for (int j = 0; j < 8; ++j) exR1[wv][j] = P[7 + j];
#pragma unroll
        for (int j = 0; j < 7; ++j) exR2b[wv][j] = P[j];
    }
    if (lane == 1) {
#pragma unroll
        for (int j = 0; j < 7; ++j) exR2a[wv][j] = P[j];
    }
    __syncthreads();

    float res[RW];
#pragma unroll
    for (int r = 0; r < RW; ++r) res[r] = P[15 + r];

    // up1: lane-1's P[23+r]   (wave edge via LDS; grid edge -> 0)
#pragma unroll
    for (int r = 0; r < 8; ++r) {
        float v = __shfl_up(P[23 + r], 1, 64);
        if (lane == 0) v = (wv > 0) ? exL1[wv - 1][r] : 0.f;
        res[r] += v;
    }
    // up2: lane-2's P[31+r], r=0..6
#pragma unroll
    for (int r = 0; r < 7; ++r) {
        float v = __shfl_up(P[31 + r], 2, 64);
        if (lane == 0)      v = (wv > 0) ? exL2a[wv - 1][r] : 0.f;
        else if (lane == 1) v = (wv > 0) ? exL2b[wv - 1][r] : 0.f;
        res[r] += v;
    }
    // down1: lane+1's P[7+r]
#pragma unroll
    for (int r = 0; r < 8; ++r) {
        float v = __shfl_down(P[7 + r], 1, 64);
        if (lane == 63) v = (wv < NWAVE - 1) ? exR1[wv + 1][r] : 0.f;
        res[r] += v;
    }
    // down2: lane+2's P[r-1], r=1..7
#pragma unroll
    for (int r = 1; r < 8; ++r) {
        float v = __shfl_down(P[r - 1], 2, 64);
        if (lane == 63)      v = (wv < NWAVE - 1) ? exR2a[wv + 1][r - 1] : 0.f;
        else if (lane == 62) v = (wv < NWAVE - 1) ? exR2b[wv + 1][r - 1] : 0.f;
        res[r] += v;
    }

    floatx4 s0, s1;
    s0.x = res[0]; s0.y = res[1]; s0.z = res[2]; s0.w = res[3];
    s1.x = res[4]; s1.y = res[5]; s1.z = res[6]; s1.w = res[7];
    float* sp = Sp + ((long)cg * BATCH + b) * L + l0;
    *reinterpret_cast<floatx4*>(sp)     = s0;
    *reinterpret_cast<floatx4*>(sp + 4) = s1;
}

// ---- K2: out[b,o,l] = sum_cg Sp[cg][b][l] — dense streaming broadcast.
__global__ __launch_bounds__(256)
void broadcast_kernel(const float* __restrict__ Sp,
                      float* __restrict__ out) {
    const int lane = threadIdx.x & 63;
    const int og   = threadIdx.x >> 6;            // 0..3
    const int b    = blockIdx.y;
    const int l4   = blockIdx.x * 64 + lane;      // float4 column index
    const long sbase = (long)b * L + (long)l4 * 4;

    floatx4 v = *reinterpret_cast<const floatx4*>(Sp + sbase);
#pragma unroll
    for (int cg = 1; cg < CG; ++cg)
        v += *reinterpret_cast<const floatx4*>(Sp + (long)cg * BATCH * L + sbase);

    float* ob = out + ((long)b * C + og * 16) * L + (long)l4 * 4;
#pragma unroll
    for (int o = 0; o < 16; ++o)
        __builtin_nontemporal_store(v, reinterpret_cast<floatx4*>(ob + (long)o * L));
}

// ---- Fallback (proven round-3 fused kernel) if ws too small ----
#define FB_R 4
#define FB_TILE (256 * FB_R)
#define FB_WIN 36
__global__ __launch_bounds__(256)
void fused_kernel(const float* __restrict__ x,
                  const float* __restrict__ w,
                  float* __restrict__ out) {
    const int tid = threadIdx.x;
    const int tile = blockIdx.x;
    const int b = blockIdx.y;
    const int l0 = tile * FB_TILE + tid * FB_R;
    float acc[FB_R] = {0.f, 0.f, 0.f, 0.f};
    const float* xb = x + (long)b * C * L;
    const bool interior = (l0 >= 16) && (l0 + 20 <= L);
    if (interior) {
        const float* xw = xb + (l0 - 16);
#pragma unroll 2
        for (int i = 0; i < C; ++i) {
            float win[FB_WIN];
            const floatx4* p = reinterpret_cast<const floatx4*>(xw + (long)i * L);
#pragma unroll
            for (int j = 0; j < FB_WIN / 4; ++j)
                reinterpret_cast<floatx4*>(win)[j] = p[j];
            const float* wp = w + i * K;
#pragma unroll
            for (int k = 0; k < K; ++k) {
                const float wk = wp[k];
#pragma unroll
                for (int r = 0; r < FB_R; ++r)
                    acc[r] += wk * win[r + 31 - k];
            }
        }
    } else {
        for (int i = 0; i < C; ++i) {
            const float* xi = xb + (long)i * L;
            float win[FB_WIN];
#pragma unroll
            for (int j = 0; j < FB_WIN; ++j) {
                const int g = l0 - 16 + j;
                win[j] = (g >= 0 && g < L) ? xi[g] : 0.f;
            }
            const float* wp = w + i * K;
#pragma unroll
            for (int k = 0; k < K; ++k) {
                const float wk = wp[k];
#pragma unroll
                for (int r = 0; r < FB_R; ++r)
                    acc[r] += wk * win[r + 31 - k];
            }
        }
    }
    float* op = out + (long)b * C * L + l0;
    floatx4 v; v.x = acc[0]; v.y = acc[1]; v.z = acc[2]; v.w = acc[3];
#pragma unroll
    for (int o = 0; o < C; ++o)
        __builtin_nontemporal_store(v, reinterpret_cast<floatx4*>(op + (long)o * L));
}

extern "C" void kernel_launch(void* const* d_in, const int* in_sizes, int n_in,
                              void* d_out, int out_size, void* d_ws, size_t ws_size,
                              hipStream_t stream) {
    const float* x = (const float*)d_in[0];   // [B, C, L] fp32
    const float* w = (const float*)d_in[1];   // [C, C, K] fp32; o=0 slice used
    float* out = (float*)d_out;               // [B, C, L] fp32

    const size_t sp_bytes = (size_t)CG * BATCH * L * sizeof(float);   // 16 MB
    if (ws_size >= sp_bytes) {
        float* Sp = (float*)d_ws;
        dim3 grid1(BATCH, CG);                    // 128 x 8 = 1024 blocks x 8 waves
        computeS_kernel<<<grid1, NT, 0, stream>>>(x, w, Sp);
        dim3 grid2(L / 256, BATCH);               // 2048 blocks
        broadcast_kernel<<<grid2, 256, 0, stream>>>(Sp, out);
    } else {
        dim3 grid(L / FB_TILE, BATCH);
        fused_kernel<<<grid, 256, 0, stream>>>(x, w, out);
    }
}